// Round 13
// baseline (102.556 us; speedup 1.0000x reference)
//
#include <hip/hip_runtime.h>
#include <hip/hip_fp16.h>

typedef _Float16 f16;
typedef __attribute__((ext_vector_type(2))) _Float16 h2v;
typedef __attribute__((ext_vector_type(8))) _Float16 f16x8;  // MFMA A/B frag
typedef __attribute__((ext_vector_type(4))) float f32x4;     // MFMA C/D frag

#define HW_    9216
#define PADP   8
#define XP_    112
#define XPXP_  12544
#define NSTEP  72                 // K-steps: 2304/32
#define NMT    288                // 64-row m-tiles (sampler granularity)
#define XT_BYTES   12845056      // 2*12544*256*2
#define BMAT_BYTES 1179648       // 72*16384
#define ATILE_B    294912        // per 64-row m-tile (2 x 147456 32-row blocks)
#define A32_B      147456        // bytes per 32-row block
#define OUTH_BYTES 9437184       // 2*256*9216*2
#define PART_BYTES 36864         // 288*16*2 f32

union U4 { uint4 u; h2v h[4]; f16x8 v; f16 f[8]; };
union U1 { unsigned u; h2v h; };
union UO { ushort4 s; f16 f[4]; };

// ---------- fast zero for xT halo ----------
__global__ __launch_bounds__(256) void k_zero(uint4* __restrict__ p) {
    int i = blockIdx.x*1024 + threadIdx.x;     // 784 blocks x 4 uint4/thread = 12,845,056 B
    uint4 z = {0u,0u,0u,0u};
    p[i] = z; p[i+256] = z; p[i+512] = z; p[i+768] = z;
}

// ---------- prep 1: x (B,C,H,W) f32 -> xT[b][y+8][x+8][c] f16, halo pre-zeroed ----------
__global__ __launch_bounds__(256) void k_prep_x(const float* __restrict__ x, f16* __restrict__ xT) {
    __shared__ float tile[64 * 97];
    int blk = blockIdx.x;                      // ((b*96)+y)*4 + cg
    int cg  = blk & 3;
    int y   = (blk >> 2) % 96;
    int b   = blk / 384;
    int t   = threadIdx.x;
    const float* src = x + (((size_t)(b*256 + cg*64))*96 + y)*96;
    for (int e = t; e < 6144; e += 256) {
        int c = e / 96, wcol = e - c*96;
        tile[c*97 + wcol] = src[(size_t)c*HW_ + wcol];
    }
    __syncthreads();
    f16* dst = xT + ((size_t)b*XPXP_ + (size_t)(y+PADP)*XP_ + PADP)*256 + cg*64;
    for (int e = t; e < 6144; e += 256) {
        int wcol = e >> 6, c = e & 63;
        dst[(size_t)wcol*256 + c] = (f16)tile[c*97 + wcol];
    }
}

// ---------- prep 2: weight (O,C,3,3) f32 -> f16 fragment-major ----------
// byte = s*16384 + nt*4096 + fn*1024 + lane*16; lane=(kq*16+r), e=c&7
__global__ __launch_bounds__(256) void k_prep_w(const float* __restrict__ wgt, f16* __restrict__ bmat) {
    int id = blockIdx.x*256 + threadIdx.x;     // < 589824 = (o*256+c)*9+k
    int o = id / 2304;
    int rem = id - o*2304;
    int c = rem / 9;
    int k = rem - c*9;
    int s  = k*8 + (c >> 5);
    int nw = o >> 6, fn = (o >> 4) & 3, r = o & 15;
    int kq = (c >> 3) & 3, e = c & 7;
    bmat[(size_t)s*8192 + nw*2048 + fn*512 + (kq*16 + r)*8 + e] = (f16)wgt[id];
}

// ---------- sampler: deformable bilinear gather -> A matrix, fragment-major ----------
__global__ __launch_bounds__(256, 6) void k_sample(
        const f16* __restrict__ xT, const float* __restrict__ offs,
        const float* __restrict__ maskp, f16* __restrict__ Ag, int mt0, int nblk)
{
    __shared__ int   geo_i[64];
    __shared__ uint4 geo_w[64];

    int blk0 = blockIdx.x;
    int blk  = (blk0 & 7)*(nblk >> 3) + (blk0 >> 3);  // XCD-chunked, bijective (nblk%8==0)
    int mtl  = blk / 9;
    int k    = blk - mtl*9;
    int mt   = mt0 + mtl;
    int b    = mt / 144;                       // 64-row tiles never cross b

    int tid = threadIdx.x;
    if (tid < 64) {
        int hw = mt*64 + tid - b*HW_;
        int h = hw / 96, w = hw - h*96;
        float offy = offs[((size_t)b*18 + 2*k    )*HW_ + hw];
        float offx = offs[((size_t)b*18 + 2*k + 1)*HW_ + hw];
        float mv   = maskp[((size_t)b*9 + k)*HW_ + hw];
        int ky = k/3 - 1, kx = k - (k/3)*3 - 1;
        float py = (float)(h + ky) + offy;
        float px = (float)(w + kx) + offx;
        py = fminf(fmaxf(py, -7.5f), 102.4f);  // keep taps inside zero halo
        px = fminf(fmaxf(px, -7.5f), 102.4f);
        float y0 = floorf(py), x0 = floorf(px);
        float dy = py - y0,   dx = px - x0;
        geo_i[tid] = (((int)y0 + PADP)*XP_ + ((int)x0 + PADP)) << 9;  // 512B/pixel
        float w00v = (1.f-dy)*(1.f-dx)*mv, w01v = (1.f-dy)*dx*mv;
        float w10v = dy*(1.f-dx)*mv,       w11v = dy*dx*mv;
        U1 p0, p1, p2, p3;
        p0.h = h2v{(f16)w00v, (f16)w00v};
        p1.h = h2v{(f16)w01v, (f16)w01v};
        p2.h = h2v{(f16)w10v, (f16)w10v};
        p3.h = h2v{(f16)w11v, (f16)w11v};
        geo_w[tid] = uint4{p0.u, p1.u, p2.u, p3.u};
    }
    __syncthreads();

    const char* xbC = (const char*)xT + (size_t)b*XPXP_*512;
    char* dst = (char*)Ag + (size_t)mtl*ATILE_B;

    #pragma unroll
    for (int j = 0; j < 8; ++j) {
        int item = tid + j*256;                // 0..2047 = 64 rows x 32 chunks(16B)
        int row = item >> 5, chunk = item & 31;
        const char* p = xbC + geo_i[row] + (chunk << 4);
        U4 t0, t1, t2, t3, oo;
        t0.u = *(const uint4*)(p);
        t1.u = *(const uint4*)(p + 512);
        t2.u = *(const uint4*)(p + XP_*512);
        t3.u = *(const uint4*)(p + XP_*512 + 512);
        U4 w4; w4.u = geo_w[row];
        h2v w00 = w4.h[0], w01 = w4.h[1], w10 = w4.h[2], w11 = w4.h[3];
        #pragma unroll
        for (int q = 0; q < 4; ++q)
            oo.h[q] = w00*t0.h[q] + w01*t1.h[q] + w10*t2.h[q] + w11*t3.h[q];
        int s = k*8 + (chunk >> 2);            // K-step (BK=32)
        size_t off = (size_t)(row >> 5)*A32_B + (size_t)s*2048
                   + ((row >> 4) & 1)*1024 + (((chunk & 3)*16 + (row & 15)) << 4);
        *(uint4*)(dst + off) = oo.u;
    }
}

// ---------- GEMM: 4-wave blocks, waves share the B n-slice (L1 dedup), split m ----------
// Block tile 256m x 64n; wave tile 64m x 64n. No LDS, no barriers — each wave streams
// its own loads; the 4 waves' B addresses are identical -> L1 serves 3 of 4.
// Per-CU traffic per step: 4x4KB A + 4KB B ~ 22.5KB (was 67.5KB).
#define MFMA16(a,b,c) __builtin_amdgcn_mfma_f32_16x16x32_f16(a,b,c,0,0,0)

#define DECLSET(P) uint4 A##P##0,A##P##1,A##P##2,A##P##3, \
                         B##P##0,B##P##1,B##P##2,B##P##3

#define LOADSET(P, s_) do { \
    const char* pa_ = aB + (size_t)(s_)*2048; \
    const char* pb_ = bB + (size_t)(s_)*16384; \
    A##P##0 = *(const uint4*)(pa_); \
    A##P##1 = *(const uint4*)(pa_ + 1024); \
    A##P##2 = *(const uint4*)(pa_ + A32_B); \
    A##P##3 = *(const uint4*)(pa_ + A32_B + 1024); \
    B##P##0 = *(const uint4*)(pb_); \
    B##P##1 = *(const uint4*)(pb_ + 1024); \
    B##P##2 = *(const uint4*)(pb_ + 2048); \
    B##P##3 = *(const uint4*)(pb_ + 3072); \
  } while (0)

#define MMROW(P, jm, Areg) do { \
    U4 xa_, xb_; xa_.u = Areg; \
    xb_.u = B##P##0; acc[jm][0] = MFMA16(xa_.v, xb_.v, acc[jm][0]); \
    xb_.u = B##P##1; acc[jm][1] = MFMA16(xa_.v, xb_.v, acc[jm][1]); \
    xb_.u = B##P##2; acc[jm][2] = MFMA16(xa_.v, xb_.v, acc[jm][2]); \
    xb_.u = B##P##3; acc[jm][3] = MFMA16(xa_.v, xb_.v, acc[jm][3]); \
  } while (0)

#define MMSET(P) do { \
    MMROW(P, 0, A##P##0); MMROW(P, 1, A##P##1); \
    MMROW(P, 2, A##P##2); MMROW(P, 3, A##P##3); \
  } while (0)

__global__ __launch_bounds__(256, 2) void k_gemm(
        const f16* __restrict__ Ag, const f16* __restrict__ bmat,
        const float* __restrict__ bias, f16* __restrict__ outh,
        float* __restrict__ part, int row0, int nblk)
{
    int b0 = blockIdx.x;
    int bb = (b0 & 7)*(nblk >> 3) + (b0 >> 3); // XCD-chunked, bijective (nblk%8==0)
    int mt = bb >> 2, nt = bb & 3;             // mt: pass-local 256-row tile; nt: 64-o slice
    int lane = threadIdx.x & 63;
    int wid  = threadIdx.x >> 6;               // 64-row m-sub within the 256-row tile

    const char* aB = (const char*)Ag + (size_t)(mt*4 + wid)*ATILE_B + lane*16;
    const char* bB = (const char*)bmat + nt*4096 + lane*16;

    f32x4 acc[4][4];
    #pragma unroll
    for (int i = 0; i < 4; ++i)
        #pragma unroll
        for (int j = 0; j < 4; ++j) acc[i][j] = (f32x4){0.f,0.f,0.f,0.f};

    DECLSET(0); DECLSET(1); DECLSET(2);

    LOADSET(0, 0);
    LOADSET(1, 1);
    LOADSET(2, 2);

    for (int s = 0; s < 69; s += 3) {
        MMSET(0);  LOADSET(0, s+3);
        MMSET(1);  LOADSET(1, s+4);
        MMSET(2);  LOADSET(2, s+5);
    }
    MMSET(0);                                  // steps 69,70,71
    MMSET(1);
    MMSET(2);

    // ---- epilogue: bias + f16 store + per-group partial stats (pure in-wave) ----
    int grow = row0 + (mt*4 + wid)*64;         // first m-row of this wave
    int t64  = grow >> 6;                      // global 64-row tile index (0..287)
    int b    = grow / HW_;
    int hwb  = grow - b*HW_;
    int ol   = lane & 15;
    int qr   = (lane >> 4) << 2;
    #pragma unroll
    for (int jm = 0; jm < 4; ++jm) {
        #pragma unroll
        for (int fn = 0; fn < 4; ++fn) {
            int o = nt*64 + fn*16 + ol;
            float bv = bias[o];
            f32x4 a = acc[jm][fn];
            a[0] += bv; a[1] += bv; a[2] += bv; a[3] += bv;
            acc[jm][fn] = a;
            UO ov;
            ov.f[0] = (f16)a[0]; ov.f[1] = (f16)a[1];
            ov.f[2] = (f16)a[2]; ov.f[3] = (f16)a[3];
            *(ushort4*)(outh + ((size_t)(b*256 + o))*HW_ + hwb + jm*16 + qr) = ov.s;
        }
    }
    #pragma unroll
    for (int fn = 0; fn < 4; ++fn) {           // group g = nt*4+fn (16 consecutive o)
        float s1 = 0.f, s2 = 0.f;
        #pragma unroll
        for (int jm = 0; jm < 4; ++jm) {
            f32x4 a = acc[jm][fn];
            s1 += a[0]+a[1]+a[2]+a[3];
            s2 += a[0]*a[0]+a[1]*a[1]+a[2]*a[2]+a[3]*a[3];
        }
        #pragma unroll
        for (int m = 32; m > 0; m >>= 1) {
            s1 += __shfl_xor(s1, m);
            s2 += __shfl_xor(s2, m);
        }
        if (lane == 0) {
            part[((size_t)t64*16 + nt*4 + fn)*2]     = s1;
            part[((size_t)t64*16 + nt*4 + fn)*2 + 1] = s2;
        }
    }
}

// ---------- finalize GN stats: 32 blocks, one per (b,g) ----------
__global__ __launch_bounds__(256) void k_finalize(const float* __restrict__ part, float* __restrict__ stats) {
    int bg = blockIdx.x, b = bg >> 4, g = bg & 15;
    float s1 = 0.f, s2 = 0.f;
    if (threadIdx.x < 144) {                   // 144 64-row tiles per image
        const float* p = part + ((size_t)(b*144 + threadIdx.x)*16 + g)*2;
        s1 = p[0]; s2 = p[1];
    }
    __shared__ float a1[256], a2[256];
    a1[threadIdx.x] = s1; a2[threadIdx.x] = s2;
    __syncthreads();
    for (int off = 128; off > 0; off >>= 1) {
        if (threadIdx.x < off) { a1[threadIdx.x] += a1[threadIdx.x+off]; a2[threadIdx.x] += a2[threadIdx.x+off]; }
        __syncthreads();
    }
    if (threadIdx.x == 0) {
        float inv_n = 1.f/147456.f;
        float mean = a1[0]*inv_n;
        float var  = fmaxf(a2[0]*inv_n - mean*mean, 0.f);
        stats[bg*2]   = mean;
        stats[bg*2+1] = rsqrtf(var + 1e-5f);
    }
}

// ---------- normalize: outh f16 -> d_out f32 (589,824 chunks -> grid 2304) ----------
__global__ __launch_bounds__(256) void k_norm(const f16* __restrict__ outh, float* __restrict__ out,
                                              const float* __restrict__ stats,
                                              const float* __restrict__ gamma, const float* __restrict__ beta) {
    int i8 = blockIdx.x*256 + threadIdx.x;             // < 589824
    int p  = i8 / 1152;                                // = b*256+o
    int o  = p & 255;
    float mean = stats[(p>>4)*2], rstd = stats[(p>>4)*2 + 1];
    float ga = gamma[o]*rstd, be = beta[o] - mean*rstd*gamma[o];
    U4 v; v.u = ((const uint4*)outh)[i8];
    float4 o0, o1;
    o0.x = (float)v.f[0]*ga + be; o0.y = (float)v.f[1]*ga + be;
    o0.z = (float)v.f[2]*ga + be; o0.w = (float)v.f[3]*ga + be;
    o1.x = (float)v.f[4]*ga + be; o1.y = (float)v.f[5]*ga + be;
    o1.z = (float)v.f[6]*ga + be; o1.w = (float)v.f[7]*ga + be;
    ((float4*)out)[i8*2]     = o0;
    ((float4*)out)[i8*2 + 1] = o1;
}

extern "C" void kernel_launch(void* const* d_in, const int* in_sizes, int n_in,
                              void* d_out, int out_size, void* d_ws, size_t ws_size,
                              hipStream_t stream) {
    const float* x      = (const float*)d_in[0];
    const float* offset = (const float*)d_in[1];
    const float* mask   = (const float*)d_in[2];
    const float* weight = (const float*)d_in[3];
    const float* bias   = (const float*)d_in[4];
    const float* gamma  = (const float*)d_in[5];
    const float* beta   = (const float*)d_in[6];
    float* out = (float*)d_out;

    char* ws = (char*)d_ws;
    f16*   xT    = (f16*)ws;                                       // 12,845,056 B
    f16*   bmat  = (f16*)(ws + XT_BYTES);                          //  1,179,648 B
    float* part  = (float*)(ws + XT_BYTES + BMAT_BYTES);           //     36,864 B
    float* stats = (float*)(ws + XT_BYTES + BMAT_BYTES + PART_BYTES);  //    256 B
    f16*   outh  = (f16*)(ws + XT_BYTES + BMAT_BYTES + PART_BYTES + 256);
    char*  Ag    = ws + XT_BYTES + BMAT_BYTES + PART_BYTES + 256 + OUTH_BYTES;

    size_t needA = (size_t)NMT * ATILE_B;                          // ~85 MB
    size_t base  = (size_t)XT_BYTES + BMAT_BYTES + PART_BYTES + 256 + OUTH_BYTES;
    size_t avail = ws_size > base ? ws_size - base : 0;
    int P = (avail >= needA) ? 1 : ((avail >= needA/2) ? 2 : 4);

    k_zero<<<784, 256, 0, stream>>>((uint4*)xT);                   // zero halo (fast fill)
    k_prep_x<<<768, 256, 0, stream>>>(x, xT);
    k_prep_w<<<2304, 256, 0, stream>>>(weight, bmat);
    int mtn = NMT / P;                         // 64-row tiles per pass (= gemm blocks per pass)
    for (int p = 0; p < P; ++p) {
        k_sample<<<mtn*9, 256, 0, stream>>>(xT, offset, mask, (f16*)Ag, p*mtn, mtn*9);
        k_gemm<<<mtn, 256, 0, stream>>>((f16*)Ag, bmat, bias, outh, part, p*mtn*64, mtn);
    }
    k_finalize<<<32, 256, 0, stream>>>(part, stats);
    k_norm<<<2304, 256, 0, stream>>>(outh, out, stats, gamma, beta);
}

// Round 14
// 87.150 us; speedup vs baseline: 1.1768x; 1.1768x over previous
//
#include <hip/hip_runtime.h>
#include <hip/hip_fp16.h>

typedef _Float16 f16;
typedef __attribute__((ext_vector_type(2))) _Float16 h2v;
typedef __attribute__((ext_vector_type(8))) _Float16 f16x8;  // MFMA A/B frag
typedef __attribute__((ext_vector_type(4))) float f32x4;     // MFMA C/D frag

#define HW_    9216
#define PADP   8
#define XP_    112
#define XPXP_  12544
#define NSTEP  72                 // K-steps: 2304/32
#define NMT    288                // 64-row m-tiles (sampler granularity)
#define XT_BYTES   12845056      // 2*12544*256*2
#define BMAT_BYTES 1179648       // 72*16384
#define ATILE_B    294912        // per 64-row m-tile (2 x 147456 32-row blocks)
#define A32_B      147456        // bytes per 32-row block
#define OUTH_BYTES 9437184       // 2*256*9216*2
#define PART_BYTES 24576         // 192*16*2 f32

union U4 { uint4 u; h2v h[4]; f16x8 v; f16 f[8]; };
union U1 { unsigned u; h2v h; };
union UO { ushort4 s; f16 f[4]; };

// ---------- fast zero for xT halo ----------
__global__ __launch_bounds__(256) void k_zero(uint4* __restrict__ p) {
    int i = blockIdx.x*1024 + threadIdx.x;     // 784 blocks x 4 uint4/thread = 12,845,056 B
    uint4 z = {0u,0u,0u,0u};
    p[i] = z; p[i+256] = z; p[i+512] = z; p[i+768] = z;
}

// ---------- prep 1: x (B,C,H,W) f32 -> xT[b][y+8][x+8][c] f16, halo pre-zeroed ----------
__global__ __launch_bounds__(256) void k_prep_x(const float* __restrict__ x, f16* __restrict__ xT) {
    __shared__ float tile[64 * 97];
    int blk = blockIdx.x;                      // ((b*96)+y)*4 + cg
    int cg  = blk & 3;
    int y   = (blk >> 2) % 96;
    int b   = blk / 384;
    int t   = threadIdx.x;
    const float* src = x + (((size_t)(b*256 + cg*64))*96 + y)*96;
    for (int e = t; e < 6144; e += 256) {
        int c = e / 96, wcol = e - c*96;
        tile[c*97 + wcol] = src[(size_t)c*HW_ + wcol];
    }
    __syncthreads();
    f16* dst = xT + ((size_t)b*XPXP_ + (size_t)(y+PADP)*XP_ + PADP)*256 + cg*64;
    for (int e = t; e < 6144; e += 256) {
        int wcol = e >> 6, c = e & 63;
        dst[(size_t)wcol*256 + c] = (f16)tile[c*97 + wcol];
    }
}

// ---------- prep 2: weight (O,C,3,3) f32 -> f16 fragment-major ----------
__global__ __launch_bounds__(256) void k_prep_w(const float* __restrict__ wgt, f16* __restrict__ bmat) {
    int id = blockIdx.x*256 + threadIdx.x;     // < 589824 = (o*256+c)*9+k
    int o = id / 2304;
    int rem = id - o*2304;
    int c = rem / 9;
    int k = rem - c*9;
    int s  = k*8 + (c >> 5);
    int nw = o >> 6, fn = (o >> 4) & 3, r = o & 15;
    int kq = (c >> 3) & 3, e = c & 7;
    bmat[(size_t)s*8192 + nw*2048 + fn*512 + (kq*16 + r)*8 + e] = (f16)wgt[id];
}

// ---------- sampler: deformable bilinear gather -> A matrix, fragment-major ----------
__global__ __launch_bounds__(256, 6) void k_sample(
        const f16* __restrict__ xT, const float* __restrict__ offs,
        const float* __restrict__ maskp, f16* __restrict__ Ag, int mt0, int nblk)
{
    __shared__ int   geo_i[64];
    __shared__ uint4 geo_w[64];

    int blk0 = blockIdx.x;
    int blk  = (blk0 & 7)*(nblk >> 3) + (blk0 >> 3);  // XCD-chunked, bijective (nblk%8==0)
    int mtl  = blk / 9;
    int k    = blk - mtl*9;
    int mt   = mt0 + mtl;
    int b    = mt / 144;                       // 64-row tiles never cross b

    int tid = threadIdx.x;
    if (tid < 64) {
        int hw = mt*64 + tid - b*HW_;
        int h = hw / 96, w = hw - h*96;
        float offy = offs[((size_t)b*18 + 2*k    )*HW_ + hw];
        float offx = offs[((size_t)b*18 + 2*k + 1)*HW_ + hw];
        float mv   = maskp[((size_t)b*9 + k)*HW_ + hw];
        int ky = k/3 - 1, kx = k - (k/3)*3 - 1;
        float py = (float)(h + ky) + offy;
        float px = (float)(w + kx) + offx;
        py = fminf(fmaxf(py, -7.5f), 102.4f);  // keep taps inside zero halo
        px = fminf(fmaxf(px, -7.5f), 102.4f);
        float y0 = floorf(py), x0 = floorf(px);
        float dy = py - y0,   dx = px - x0;
        geo_i[tid] = (((int)y0 + PADP)*XP_ + ((int)x0 + PADP)) << 9;  // 512B/pixel
        float w00v = (1.f-dy)*(1.f-dx)*mv, w01v = (1.f-dy)*dx*mv;
        float w10v = dy*(1.f-dx)*mv,       w11v = dy*dx*mv;
        U1 p0, p1, p2, p3;
        p0.h = h2v{(f16)w00v, (f16)w00v};
        p1.h = h2v{(f16)w01v, (f16)w01v};
        p2.h = h2v{(f16)w10v, (f16)w10v};
        p3.h = h2v{(f16)w11v, (f16)w11v};
        geo_w[tid] = uint4{p0.u, p1.u, p2.u, p3.u};
    }
    __syncthreads();

    const char* xbC = (const char*)xT + (size_t)b*XPXP_*512;
    char* dst = (char*)Ag + (size_t)mtl*ATILE_B;

    #pragma unroll
    for (int j = 0; j < 8; ++j) {
        int item = tid + j*256;                // 0..2047 = 64 rows x 32 chunks(16B)
        int row = item >> 5, chunk = item & 31;
        const char* p = xbC + geo_i[row] + (chunk << 4);
        U4 t0, t1, t2, t3, oo;
        t0.u = *(const uint4*)(p);
        t1.u = *(const uint4*)(p + 512);
        t2.u = *(const uint4*)(p + XP_*512);
        t3.u = *(const uint4*)(p + XP_*512 + 512);
        U4 w4; w4.u = geo_w[row];
        h2v w00 = w4.h[0], w01 = w4.h[1], w10 = w4.h[2], w11 = w4.h[3];
        #pragma unroll
        for (int q = 0; q < 4; ++q)
            oo.h[q] = w00*t0.h[q] + w01*t1.h[q] + w10*t2.h[q] + w11*t3.h[q];
        int s = k*8 + (chunk >> 2);            // K-step (BK=32)
        size_t off = (size_t)(row >> 5)*A32_B + (size_t)s*2048
                   + ((row >> 4) & 1)*1024 + (((chunk & 3)*16 + (row & 15)) << 4);
        *(uint4*)(dst + off) = oo.u;
    }
}

// ---------- GEMM: one independent wave per block, NO LDS, NO barriers ----------
// Wave tile 96(m) x 64(o): per step 6 A-frag + 4 B-frag loads + 24 MFMA.
// 4-deep rotating register sets (load->use distance ~480cy ~ L2 latency).
#define MFMA16(a,b,c) __builtin_amdgcn_mfma_f32_16x16x32_f16(a,b,c,0,0,0)

#define DECLSET(P) uint4 A##P##0,A##P##1,A##P##2,A##P##3,A##P##4,A##P##5, \
                         B##P##0,B##P##1,B##P##2,B##P##3

#define LOADSET(P, s_) do { \
    const char* pa_ = aB + (size_t)(s_)*2048; \
    const char* pb_ = bB + (size_t)(s_)*16384; \
    A##P##0 = *(const uint4*)(pa_); \
    A##P##1 = *(const uint4*)(pa_ + 1024); \
    A##P##2 = *(const uint4*)(pa_ + A32_B); \
    A##P##3 = *(const uint4*)(pa_ + A32_B + 1024); \
    A##P##4 = *(const uint4*)(pa_ + 2*A32_B); \
    A##P##5 = *(const uint4*)(pa_ + 2*A32_B + 1024); \
    B##P##0 = *(const uint4*)(pb_); \
    B##P##1 = *(const uint4*)(pb_ + 1024); \
    B##P##2 = *(const uint4*)(pb_ + 2048); \
    B##P##3 = *(const uint4*)(pb_ + 3072); \
  } while (0)

#define MMROW(P, jm, Areg) do { \
    U4 xa_, xb_; xa_.u = Areg; \
    xb_.u = B##P##0; acc[jm][0] = MFMA16(xa_.v, xb_.v, acc[jm][0]); \
    xb_.u = B##P##1; acc[jm][1] = MFMA16(xa_.v, xb_.v, acc[jm][1]); \
    xb_.u = B##P##2; acc[jm][2] = MFMA16(xa_.v, xb_.v, acc[jm][2]); \
    xb_.u = B##P##3; acc[jm][3] = MFMA16(xa_.v, xb_.v, acc[jm][3]); \
  } while (0)

#define MMSET(P) do { \
    MMROW(P, 0, A##P##0); MMROW(P, 1, A##P##1); MMROW(P, 2, A##P##2); \
    MMROW(P, 3, A##P##3); MMROW(P, 4, A##P##4); MMROW(P, 5, A##P##5); \
  } while (0)

__global__ __launch_bounds__(64, 1) void k_gemm(
        const f16* __restrict__ Ag, const f16* __restrict__ bmat,
        const float* __restrict__ bias, f16* __restrict__ outh,
        float* __restrict__ part, int row0, int nwv)
{
    int w0 = blockIdx.x;
    int w  = (w0 & 7)*(nwv >> 3) + (w0 >> 3);  // keeps the 4 n-waves of one mw on one XCD
    int mwl = w >> 2, nw = w & 3;              // mwl: pass-local 96-row tile
    int lane = threadIdx.x;

    const char* aB = (const char*)Ag + (size_t)mwl*(3*A32_B) + lane*16;
    const char* bB = (const char*)bmat + nw*4096 + lane*16;

    f32x4 acc[6][4];
    #pragma unroll
    for (int i = 0; i < 6; ++i)
        #pragma unroll
        for (int j = 0; j < 4; ++j) acc[i][j] = (f32x4){0.f,0.f,0.f,0.f};

    DECLSET(0); DECLSET(1); DECLSET(2); DECLSET(3);

    LOADSET(0, 0);
    LOADSET(1, 1);
    LOADSET(2, 2);
    LOADSET(3, 3);

    for (int s = 0; s < 68; s += 4) {
        MMSET(0);  LOADSET(0, s+4);
        MMSET(1);  LOADSET(1, s+5);
        MMSET(2);  LOADSET(2, s+6);
        MMSET(3);  LOADSET(3, s+7);
    }
    MMSET(0);                                  // steps 68..71
    MMSET(1);
    MMSET(2);
    MMSET(3);

    // ---- epilogue: bias + f16 store + per-group partial stats (pure in-wave) ----
    int grow = row0 + mwl*96;                  // global first m-row of this wave
    int mwg  = grow / 96;                      // global 96-row tile index (0..191)
    int b    = grow / HW_;
    int hwb  = grow - b*HW_;
    int ol   = lane & 15;
    int qr   = (lane >> 4) << 2;
    #pragma unroll
    for (int jm = 0; jm < 6; ++jm) {
        #pragma unroll
        for (int fn = 0; fn < 4; ++fn) {
            int o = nw*64 + fn*16 + ol;
            float bv = bias[o];
            f32x4 a = acc[jm][fn];
            a[0] += bv; a[1] += bv; a[2] += bv; a[3] += bv;
            acc[jm][fn] = a;
            UO ov;
            ov.f[0] = (f16)a[0]; ov.f[1] = (f16)a[1];
            ov.f[2] = (f16)a[2]; ov.f[3] = (f16)a[3];
            *(ushort4*)(outh + ((size_t)(b*256 + o))*HW_ + hwb + jm*16 + qr) = ov.s;
        }
    }
    #pragma unroll
    for (int fn = 0; fn < 4; ++fn) {           // group g = nw*4+fn (16 consecutive o)
        float s1 = 0.f, s2 = 0.f;
        #pragma unroll
        for (int jm = 0; jm < 6; ++jm) {
            f32x4 a = acc[jm][fn];
            s1 += a[0]+a[1]+a[2]+a[3];
            s2 += a[0]*a[0]+a[1]*a[1]+a[2]*a[2]+a[3]*a[3];
        }
        #pragma unroll
        for (int m = 32; m > 0; m >>= 1) {
            s1 += __shfl_xor(s1, m);
            s2 += __shfl_xor(s2, m);
        }
        if (lane == 0) {
            part[((size_t)mwg*16 + nw*4 + fn)*2]     = s1;
            part[((size_t)mwg*16 + nw*4 + fn)*2 + 1] = s2;
        }
    }
}

// ---------- finalize GN stats: 32 blocks, one per (b,g) ----------
__global__ __launch_bounds__(256) void k_finalize(const float* __restrict__ part, float* __restrict__ stats) {
    int bg = blockIdx.x, b = bg >> 4, g = bg & 15;
    float s1 = 0.f, s2 = 0.f;
    if (threadIdx.x < 96) {                    // 96 96-row tiles per image
        const float* p = part + ((size_t)(b*96 + threadIdx.x)*16 + g)*2;
        s1 = p[0]; s2 = p[1];
    }
    __shared__ float a1[256], a2[256];
    a1[threadIdx.x] = s1; a2[threadIdx.x] = s2;
    __syncthreads();
    for (int off = 128; off > 0; off >>= 1) {
        if (threadIdx.x < off) { a1[threadIdx.x] += a1[threadIdx.x+off]; a2[threadIdx.x] += a2[threadIdx.x+off]; }
        __syncthreads();
    }
    if (threadIdx.x == 0) {
        float inv_n = 1.f/147456.f;
        float mean = a1[0]*inv_n;
        float var  = fmaxf(a2[0]*inv_n - mean*mean, 0.f);
        stats[bg*2]   = mean;
        stats[bg*2+1] = rsqrtf(var + 1e-5f);
    }
}

// ---------- normalize: outh f16 -> d_out f32 (589,824 chunks -> grid 2304) ----------
__global__ __launch_bounds__(256) void k_norm(const f16* __restrict__ outh, float* __restrict__ out,
                                              const float* __restrict__ stats,
                                              const float* __restrict__ gamma, const float* __restrict__ beta) {
    int i8 = blockIdx.x*256 + threadIdx.x;             // < 589824
    int p  = i8 / 1152;                                // = b*256+o
    int o  = p & 255;
    float mean = stats[(p>>4)*2], rstd = stats[(p>>4)*2 + 1];
    float ga = gamma[o]*rstd, be = beta[o] - mean*rstd*gamma[o];
    U4 v; v.u = ((const uint4*)outh)[i8];
    float4 o0, o1;
    o0.x = (float)v.f[0]*ga + be; o0.y = (float)v.f[1]*ga + be;
    o0.z = (float)v.f[2]*ga + be; o0.w = (float)v.f[3]*ga + be;
    o1.x = (float)v.f[4]*ga + be; o1.y = (float)v.f[5]*ga + be;
    o1.z = (float)v.f[6]*ga + be; o1.w = (float)v.f[7]*ga + be;
    ((float4*)out)[i8*2]     = o0;
    ((float4*)out)[i8*2 + 1] = o1;
}

extern "C" void kernel_launch(void* const* d_in, const int* in_sizes, int n_in,
                              void* d_out, int out_size, void* d_ws, size_t ws_size,
                              hipStream_t stream) {
    const float* x      = (const float*)d_in[0];
    const float* offset = (const float*)d_in[1];
    const float* mask   = (const float*)d_in[2];
    const float* weight = (const float*)d_in[3];
    const float* bias   = (const float*)d_in[4];
    const float* gamma  = (const float*)d_in[5];
    const float* beta   = (const float*)d_in[6];
    float* out = (float*)d_out;

    char* ws = (char*)d_ws;
    f16*   xT    = (f16*)ws;                                       // 12,845,056 B
    f16*   bmat  = (f16*)(ws + XT_BYTES);                          //  1,179,648 B
    float* part  = (float*)(ws + XT_BYTES + BMAT_BYTES);           //     24,576 B
    float* stats = (float*)(ws + XT_BYTES + BMAT_BYTES + PART_BYTES);  //    256 B
    f16*   outh  = (f16*)(ws + XT_BYTES + BMAT_BYTES + PART_BYTES + 256);
    char*  Ag    = ws + XT_BYTES + BMAT_BYTES + PART_BYTES + 256 + OUTH_BYTES;

    size_t needA = (size_t)NMT * ATILE_B;                          // ~85 MB
    size_t base  = (size_t)XT_BYTES + BMAT_BYTES + PART_BYTES + 256 + OUTH_BYTES;
    size_t avail = ws_size > base ? ws_size - base : 0;
    int P = (avail >= needA) ? 1 : ((avail >= needA/2) ? 2 : 4);

    k_zero<<<784, 256, 0, stream>>>((uint4*)xT);                   // zero halo (fast fill)
    k_prep_x<<<768, 256, 0, stream>>>(x, xT);
    k_prep_w<<<2304, 256, 0, stream>>>(weight, bmat);
    int mtn = NMT / P;                         // 64-row tiles per pass
    int nwv = 768 / P;                         // gemm waves per pass
    for (int p = 0; p < P; ++p) {
        k_sample<<<mtn*9, 256, 0, stream>>>(xT, offset, mask, (f16*)Ag, p*mtn, mtn*9);
        k_gemm<<<nwv, 64, 0, stream>>>((f16*)Ag, bmat, bias, outh, part, p*mtn*64, nwv);
    }
    k_finalize<<<32, 256, 0, stream>>>(part, stats);
    k_norm<<<2304, 256, 0, stream>>>(outh, out, stats, gamma, beta);
}